// Round 1
// baseline (146.954 us; speedup 1.0000x reference)
//
#include <hip/hip_runtime.h>
#include <hip/hip_bf16.h>

// Problem constants
#define BB 8
#define TT 2048
#define CC 1024
#define HH 64

typedef float f32x4 __attribute__((ext_vector_type(4)));
typedef short s16x8 __attribute__((ext_vector_type(8)));   // 8 bf16 in 4 VGPRs

// fp32 -> bf16 (RNE), pure bit math (matches v_cvt_pk_bf16_f32 rounding)
static __device__ __forceinline__ unsigned short f2bf(float f) {
    unsigned int u = __float_as_uint(f);
    u = (u + 0x7FFFu + ((u >> 16) & 1u)) >> 16;
    return (unsigned short)u;
}

// ---------------------------------------------------------------------------
// Kernel 0: transpose + convert Wq|Wk|Wv [1024][64] fp32 -> wT [192][1024] bf16
// wT[n][c] = W_{n/64}[c][n%64]
// ---------------------------------------------------------------------------
__global__ __launch_bounds__(256) void wt_kernel(
    const float* __restrict__ Wq, const float* __restrict__ Wk,
    const float* __restrict__ Wv, unsigned short* __restrict__ wT) {
    __shared__ unsigned short lds[64][72];  // [h][cc], padded
    int sel = blockIdx.x >> 4;          // 0..2 (q,k,v)
    int c0  = (blockIdx.x & 15) * 64;   // C tile base
    const float* W = (sel == 0) ? Wq : ((sel == 1) ? Wk : Wv);
    int t = threadIdx.x;
#pragma unroll
    for (int i = 0; i < 4; ++i) {
        int u = t + 256 * i;            // float4 unit within [64 c][16 h4]
        int cc = u >> 4, h4 = (u & 15) * 4;
        const float4 v = *reinterpret_cast<const float4*>(&W[(size_t)(c0 + cc) * HH + h4]);
        lds[h4 + 0][cc] = f2bf(v.x);
        lds[h4 + 1][cc] = f2bf(v.y);
        lds[h4 + 2][cc] = f2bf(v.z);
        lds[h4 + 3][cc] = f2bf(v.w);
    }
    __syncthreads();
#pragma unroll
    for (int i = 0; i < 4; ++i) {
        int u = t + 256 * i;
        int h = u >> 4, c4 = (u & 15) * 4;
        unsigned short* dst = &wT[(size_t)(sel * 64 + h) * CC + c0 + c4];
        dst[0] = lds[h][c4 + 0];
        dst[1] = lds[h][c4 + 1];
        dst[2] = lds[h][c4 + 2];
        dst[3] = lds[h][c4 + 3];
    }
}

// ---------------------------------------------------------------------------
// Kernel 1: QKV projection GEMM.  C[16384][192] = X[16384][1024] @ wT^T
// 1024 one-wave blocks; each wave: 64 rows x 48 cols, BK=64, 16 K-chunks.
// Outputs: q,k row-major bf16 [B*T][64]; v transposed bf16 [B][64][T].
// ---------------------------------------------------------------------------
__global__ __launch_bounds__(64) void qkv_kernel(
    const float* __restrict__ x, const unsigned short* __restrict__ wT,
    unsigned short* __restrict__ qo, unsigned short* __restrict__ ko,
    unsigned short* __restrict__ vT) {
    const int lane = threadIdx.x;
    const int lo = lane & 15, hi = lane >> 4;
    const int rb = (blockIdx.x >> 2) * 64;   // row tile base (M)
    const int w  = blockIdx.x & 3;           // col group
    const int cb = w * 48;                   // col base (N)

    f32x4 acc[4][3];
#pragma unroll
    for (int m = 0; m < 4; ++m)
#pragma unroll
        for (int n = 0; n < 3; ++n) acc[m][n] = (f32x4){0.f, 0.f, 0.f, 0.f};

    for (int c = 0; c < 16; ++c) {
        const int k0 = c * 64;
        // A-frags: X rows -> bf16 (lane: row=lo, k=8*hi+j (+32 for kh=1))
        s16x8 a[4][2];
#pragma unroll
        for (int m = 0; m < 4; ++m) {
            const float* xp = &x[(size_t)(rb + 16 * m + lo) * CC + k0 + 8 * hi];
#pragma unroll
            for (int kh = 0; kh < 2; ++kh) {
                float4 f0 = *reinterpret_cast<const float4*>(xp + 32 * kh);
                float4 f1 = *reinterpret_cast<const float4*>(xp + 32 * kh + 4);
                s16x8 v;
                v[0] = (short)f2bf(f0.x); v[1] = (short)f2bf(f0.y);
                v[2] = (short)f2bf(f0.z); v[3] = (short)f2bf(f0.w);
                v[4] = (short)f2bf(f1.x); v[5] = (short)f2bf(f1.y);
                v[6] = (short)f2bf(f1.z); v[7] = (short)f2bf(f1.w);
                a[m][kh] = v;
            }
        }
        // B-frags direct from global wT (L2-hot), then MFMA
#pragma unroll
        for (int n = 0; n < 3; ++n) {
            const unsigned short* wp = &wT[(size_t)(cb + 16 * n + lo) * CC + k0 + 8 * hi];
            s16x8 b0 = *reinterpret_cast<const s16x8*>(wp);
            s16x8 b1 = *reinterpret_cast<const s16x8*>(wp + 32);
#pragma unroll
            for (int m = 0; m < 4; ++m) {
                acc[m][n] = __builtin_amdgcn_mfma_f32_16x16x32_bf16(a[m][0], b0, acc[m][n], 0, 0, 0);
                acc[m][n] = __builtin_amdgcn_mfma_f32_16x16x32_bf16(a[m][1], b1, acc[m][n], 0, 0, 0);
            }
        }
    }
    // Epilogue: C/D layout col=lo, row=4*hi+r
#pragma unroll
    for (int n = 0; n < 3; ++n) {
        const int col = cb + 16 * n + lo;   // 0..191
#pragma unroll
        for (int m = 0; m < 4; ++m) {
#pragma unroll
            for (int r = 0; r < 4; ++r) {
                const int row = rb + 16 * m + 4 * hi + r;  // global token
                unsigned short bv = f2bf(acc[m][n][r]);
                if (col < 64) {
                    qo[(size_t)row * HH + col] = bv;
                } else if (col < 128) {
                    ko[(size_t)row * HH + (col - 64)] = bv;
                } else {
                    const int bat = row >> 11, t = row & (TT - 1);
                    vT[((size_t)(bat * HH + (col - 128))) * TT + t] = bv;
                }
            }
        }
    }
}

// ---------------------------------------------------------------------------
// Kernel 2: flash attention. 256 blocks x 4 independent waves.
// Wave = one 16-row q tile; kv tiles of 64; online softmax; PV via LDS P.
// qt16 assignment {j, 63-j, 64+j, 127-j} balances work exactly per block.
// ---------------------------------------------------------------------------
__global__ __launch_bounds__(256) void attn_kernel(
    const unsigned short* __restrict__ Q, const unsigned short* __restrict__ K,
    const unsigned short* __restrict__ Vt, float* __restrict__ out) {
    __shared__ unsigned short Plds[4][16][72];  // per-wave P tile, padded (2-way conflicts only)
    const int tid = threadIdx.x;
    const int wv = tid >> 6, lane = tid & 63;
    const int lo = lane & 15, hi = lane >> 4;
    const int b = blockIdx.x >> 5, j = blockIdx.x & 31;
    int qt;
    if (wv == 0) qt = j;
    else if (wv == 1) qt = 63 - j;
    else if (wv == 2) qt = 64 + j;
    else qt = 127 - j;
    const int wqb = qt * 16;  // q-row base for this wave

    // Q A-frags (row=lo, k(h)=8*hi+j, +32 for second half)
    const unsigned short* qp = &Q[((size_t)(b * TT) + wqb + lo) * HH + 8 * hi];
    const s16x8 qf0 = *reinterpret_cast<const s16x8*>(qp);
    const s16x8 qf1 = *reinterpret_cast<const s16x8*>(qp + 32);

    f32x4 o[4];
#pragma unroll
    for (int nt = 0; nt < 4; ++nt) o[nt] = (f32x4){0.f, 0.f, 0.f, 0.f};
    float mrun[4] = {-1e30f, -1e30f, -1e30f, -1e30f};
    float lsum[4] = {0.f, 0.f, 0.f, 0.f};

    const int ntile = qt / 4 + 1;
    for (int t = 0; t < ntile; ++t) {
        const int kv = t * 64;
        // QK^T: S[16 q][64 key]
        f32x4 s[4];
#pragma unroll
        for (int nt = 0; nt < 4; ++nt) {
            const unsigned short* kp = &K[((size_t)(b * TT) + kv + 16 * nt + lo) * HH + 8 * hi];
            s16x8 kf0 = *reinterpret_cast<const s16x8*>(kp);
            s16x8 kf1 = *reinterpret_cast<const s16x8*>(kp + 32);
            f32x4 z = (f32x4){0.f, 0.f, 0.f, 0.f};
            z = __builtin_amdgcn_mfma_f32_16x16x32_bf16(qf0, kf0, z, 0, 0, 0);
            z = __builtin_amdgcn_mfma_f32_16x16x32_bf16(qf1, kf1, z, 0, 0, 0);
            s[nt] = z;
        }
        const bool domask = (kv + 63) > wqb;
        float sc[4][4];
#pragma unroll
        for (int nt = 0; nt < 4; ++nt)
#pragma unroll
            for (int r = 0; r < 4; ++r) {
                float v = s[nt][r] * 0.125f;  // H^-0.5
                if (domask) {
                    const int key = kv + 16 * nt + lo;
                    const int row = wqb + 4 * hi + r;
                    if (key > row) v = -1e30f;
                }
                sc[nt][r] = v;
            }
        // online softmax (row r lives in 16-lane group; butterfly over masks 1,2,4,8)
        float mnew[4], alpha[4], rs[4];
#pragma unroll
        for (int r = 0; r < 4; ++r) {
            float mx = fmaxf(fmaxf(sc[0][r], sc[1][r]), fmaxf(sc[2][r], sc[3][r]));
            mx = fmaxf(mx, __shfl_xor(mx, 1));
            mx = fmaxf(mx, __shfl_xor(mx, 2));
            mx = fmaxf(mx, __shfl_xor(mx, 4));
            mx = fmaxf(mx, __shfl_xor(mx, 8));
            mnew[r] = fmaxf(mrun[r], mx);
            alpha[r] = exp2f((mrun[r] - mnew[r]) * 1.44269504f);
            mrun[r] = mnew[r];
            rs[r] = 0.f;
        }
#pragma unroll
        for (int nt = 0; nt < 4; ++nt)
#pragma unroll
            for (int r = 0; r < 4; ++r) {
                float p = exp2f((sc[nt][r] - mnew[r]) * 1.44269504f);
                rs[r] += p;
                Plds[wv][4 * hi + r][16 * nt + lo] = f2bf(p);
            }
#pragma unroll
        for (int r = 0; r < 4; ++r) {
            rs[r] += __shfl_xor(rs[r], 1);
            rs[r] += __shfl_xor(rs[r], 2);
            rs[r] += __shfl_xor(rs[r], 4);
            rs[r] += __shfl_xor(rs[r], 8);
            lsum[r] = lsum[r] * alpha[r] + rs[r];
        }
#pragma unroll
        for (int nt = 0; nt < 4; ++nt)
#pragma unroll
            for (int r = 0; r < 4; ++r) o[nt][r] *= alpha[r];
        // PV: O[16 q][64 h] += P[16][64] @ V[64][64]
        const s16x8 pa0 = *reinterpret_cast<const s16x8*>(&Plds[wv][lo][8 * hi]);
        const s16x8 pa1 = *reinterpret_cast<const s16x8*>(&Plds[wv][lo][8 * hi + 32]);
#pragma unroll
        for (int nt = 0; nt < 4; ++nt) {
            const unsigned short* vp = &Vt[((size_t)(b * HH) + 16 * nt + lo) * TT + kv + 8 * hi];
            s16x8 v0 = *reinterpret_cast<const s16x8*>(vp);
            s16x8 v1 = *reinterpret_cast<const s16x8*>(vp + 32);
            o[nt] = __builtin_amdgcn_mfma_f32_16x16x32_bf16(pa0, v0, o[nt], 0, 0, 0);
            o[nt] = __builtin_amdgcn_mfma_f32_16x16x32_bf16(pa1, v1, o[nt], 0, 0, 0);
        }
    }
    // epilogue
#pragma unroll
    for (int nt = 0; nt < 4; ++nt)
#pragma unroll
        for (int r = 0; r < 4; ++r) {
            const int row = wqb + 4 * hi + r;
            out[((size_t)(b * TT) + row) * HH + 16 * nt + lo] = o[nt][r] / lsum[r];
        }
}

extern "C" void kernel_launch(void* const* d_in, const int* in_sizes, int n_in,
                              void* d_out, int out_size, void* d_ws, size_t ws_size,
                              hipStream_t stream) {
    (void)in_sizes; (void)n_in; (void)out_size; (void)ws_size;
    const float* x  = (const float*)d_in[0];
    const float* Wq = (const float*)d_in[1];
    const float* Wk = (const float*)d_in[2];
    const float* Wv = (const float*)d_in[3];
    float* out = (float*)d_out;

    char* ws = (char*)d_ws;
    unsigned short* wT = (unsigned short*)ws;                       // 192*1024*2 = 384 KB
    unsigned short* q  = (unsigned short*)(ws + 393216);            // 2 MB
    unsigned short* k  = (unsigned short*)(ws + 393216 + 2097152);  // 2 MB
    unsigned short* vT = (unsigned short*)(ws + 393216 + 4194304);  // 2 MB

    wt_kernel<<<48, 256, 0, stream>>>(Wq, Wk, Wv, wT);
    qkv_kernel<<<1024, 64, 0, stream>>>(x, wT, q, k, vT);
    attn_kernel<<<256, 256, 0, stream>>>(q, k, vT, out);
}

// Round 2
// 101.638 us; speedup vs baseline: 1.4459x; 1.4459x over previous
//
#include <hip/hip_runtime.h>
#include <hip/hip_bf16.h>

// Problem constants
#define BB 8
#define TT 2048
#define CC 1024
#define HH 64

typedef float f32x4 __attribute__((ext_vector_type(4)));
typedef short s16x8 __attribute__((ext_vector_type(8)));   // 8 bf16 in 4 VGPRs

// fp32 -> bf16 (RNE), pure bit math
static __device__ __forceinline__ unsigned short f2bf(float f) {
    unsigned int u = __float_as_uint(f);
    u = (u + 0x7FFFu + ((u >> 16) & 1u)) >> 16;
    return (unsigned short)u;
}

// ---------------------------------------------------------------------------
// Kernel 0: transpose + convert Wq|Wk|Wv [1024][64] fp32 -> wT [192][1024] bf16
// ---------------------------------------------------------------------------
__global__ __launch_bounds__(256) void wt_kernel(
    const float* __restrict__ Wq, const float* __restrict__ Wk,
    const float* __restrict__ Wv, unsigned short* __restrict__ wT) {
    __shared__ unsigned short lds[64][72];
    int sel = blockIdx.x >> 4;          // 0..2 (q,k,v)
    int c0  = (blockIdx.x & 15) * 64;   // C tile base
    const float* W = (sel == 0) ? Wq : ((sel == 1) ? Wk : Wv);
    int t = threadIdx.x;
#pragma unroll
    for (int i = 0; i < 4; ++i) {
        int u = t + 256 * i;
        int cc = u >> 4, h4 = (u & 15) * 4;
        const float4 v = *reinterpret_cast<const float4*>(&W[(size_t)(c0 + cc) * HH + h4]);
        lds[h4 + 0][cc] = f2bf(v.x);
        lds[h4 + 1][cc] = f2bf(v.y);
        lds[h4 + 2][cc] = f2bf(v.z);
        lds[h4 + 3][cc] = f2bf(v.w);
    }
    __syncthreads();
#pragma unroll
    for (int i = 0; i < 4; ++i) {
        int u = t + 256 * i;
        int h = u >> 4, c4 = (u & 15) * 4;
        unsigned short* dst = &wT[(size_t)(sel * 64 + h) * CC + c0 + c4];
        dst[0] = lds[h][c4 + 0];
        dst[1] = lds[h][c4 + 1];
        dst[2] = lds[h][c4 + 2];
        dst[3] = lds[h][c4 + 3];
    }
}

// ---------------------------------------------------------------------------
// Kernel 1: QKV projection GEMM.  C[16384][192] = X[16384][1024] @ wT^T
// 512 blocks x 8 waves (512 thr). Block = 32-row M tile. Wave (wm,wn):
// rows rb+16*wm.., cols wn*48.. . x chunk staged to bf16 LDS once (shared cvt).
// ---------------------------------------------------------------------------
__global__ __launch_bounds__(512) void qkv_kernel(
    const float* __restrict__ x, const unsigned short* __restrict__ wT,
    unsigned short* __restrict__ qo, unsigned short* __restrict__ ko,
    unsigned short* __restrict__ vT) {
    __shared__ unsigned short xb[32][72];   // 32 rows x 64 k, padded (stride 144B)
    const int tid = threadIdx.x;
    const int wv = tid >> 6, lane = tid & 63;
    const int lo = lane & 15, hi = lane >> 4;
    const int wm = wv >> 2, wn = wv & 3;
    const int rb = blockIdx.x * 32;
    const int cb = wn * 48;
    const int srow = tid >> 4, scol = (tid & 15) * 4;  // staging assignment

    f32x4 acc[3];
#pragma unroll
    for (int n = 0; n < 3; ++n) acc[n] = (f32x4){0.f, 0.f, 0.f, 0.f};

    for (int c = 0; c < 16; ++c) {
        const int k0 = c * 64;
        // load x chunk [32][64] f32 (1 float4 / thread)
        const float4 f = *reinterpret_cast<const float4*>(&x[(size_t)(rb + srow) * CC + k0 + scol]);
        __syncthreads();   // previous chunk's reads complete
        ushort4 pk;
        pk.x = f2bf(f.x); pk.y = f2bf(f.y); pk.z = f2bf(f.z); pk.w = f2bf(f.w);
        *reinterpret_cast<ushort4*>(&xb[srow][scol]) = pk;
        __syncthreads();
        // A frags from LDS (row = 16*wm + lo, k = 8*hi + j  (+32))
        const s16x8 a0 = *reinterpret_cast<const s16x8*>(&xb[16 * wm + lo][8 * hi]);
        const s16x8 a1 = *reinterpret_cast<const s16x8*>(&xb[16 * wm + lo][32 + 8 * hi]);
#pragma unroll
        for (int n = 0; n < 3; ++n) {
            const unsigned short* wp = &wT[(size_t)(cb + 16 * n + lo) * CC + k0 + 8 * hi];
            const s16x8 b0 = *reinterpret_cast<const s16x8*>(wp);
            const s16x8 b1 = *reinterpret_cast<const s16x8*>(wp + 32);
            acc[n] = __builtin_amdgcn_mfma_f32_16x16x32_bf16(a0, b0, acc[n], 0, 0, 0);
            acc[n] = __builtin_amdgcn_mfma_f32_16x16x32_bf16(a1, b1, acc[n], 0, 0, 0);
        }
    }
    // Epilogue: C/D layout col=lo, row=4*hi+r
#pragma unroll
    for (int n = 0; n < 3; ++n) {
        const int col = cb + 16 * n + lo;   // 0..191
#pragma unroll
        for (int r = 0; r < 4; ++r) {
            const int row = rb + 16 * wm + 4 * hi + r;
            const unsigned short bv = f2bf(acc[n][r]);
            if (col < 64) {
                qo[(size_t)row * HH + col] = bv;
            } else if (col < 128) {
                ko[(size_t)row * HH + (col - 64)] = bv;
            } else {
                const int bat = row >> 11, t = row & (TT - 1);
                vT[((size_t)(bat * HH + (col - 128))) * TT + t] = bv;
            }
        }
    }
}

// ---------------------------------------------------------------------------
// Kernel 2: flash attention. 1024 blocks (8 batch x 128 q-tiles) x 8 waves.
// All 8 waves share ONE 16-row q tile; wave s handles kv tiles t=s,s+8,...
// (strided -> balanced). Per-wave online softmax partials (o,m,l) combined
// in LDS at the end. Largest q-tiles launch first; bid&7 = batch -> XCD.
// ---------------------------------------------------------------------------
__global__ __launch_bounds__(512) void attn_kernel(
    const unsigned short* __restrict__ Q, const unsigned short* __restrict__ K,
    const unsigned short* __restrict__ Vt, float* __restrict__ out) {
    // LDS: Plds [8][16][72] u16 (18432 B) aliases Of [8][16][68] f32 (34816 B);
    // Mm/Ml after. Total 35840 B -> 4 blocks/CU.
    __shared__ __align__(16) char smem[35840];
    unsigned short (*Plds)[16][72] = reinterpret_cast<unsigned short(*)[16][72]>(smem);
    float (*Of)[16][68] = reinterpret_cast<float(*)[16][68]>(smem);
    float (*Mm)[16] = reinterpret_cast<float(*)[16]>(smem + 34816);
    float (*Ml)[16] = reinterpret_cast<float(*)[16]>(smem + 34816 + 512);

    const int tid = threadIdx.x;
    const int wv = tid >> 6, lane = tid & 63;
    const int lo = lane & 15, hi = lane >> 4;
    const int b = blockIdx.x & 7;              // batch -> XCD locality
    const int qt = 127 - (blockIdx.x >> 3);    // largest work first
    const int wqb = qt * 16;                   // q-row base (16 rows per block)

    // Q A-frags (shared by all waves; row=lo, k=8*hi+j, +32)
    const unsigned short* qp = &Q[((size_t)(b * TT) + wqb + lo) * HH + 8 * hi];
    const s16x8 qf0 = *reinterpret_cast<const s16x8*>(qp);
    const s16x8 qf1 = *reinterpret_cast<const s16x8*>(qp + 32);

    f32x4 o[4];
#pragma unroll
    for (int nt = 0; nt < 4; ++nt) o[nt] = (f32x4){0.f, 0.f, 0.f, 0.f};
    float mrun[4] = {-1e30f, -1e30f, -1e30f, -1e30f};
    float lsum[4] = {0.f, 0.f, 0.f, 0.f};

    const int ntile = qt / 4 + 1;
    for (int t = wv; t < ntile; t += 8) {
        const int kv = t * 64;
        // QK^T: S[16 q][64 key]
        f32x4 s[4];
#pragma unroll
        for (int nt = 0; nt < 4; ++nt) {
            const unsigned short* kp = &K[((size_t)(b * TT) + kv + 16 * nt + lo) * HH + 8 * hi];
            const s16x8 kf0 = *reinterpret_cast<const s16x8*>(kp);
            const s16x8 kf1 = *reinterpret_cast<const s16x8*>(kp + 32);
            f32x4 z = (f32x4){0.f, 0.f, 0.f, 0.f};
            z = __builtin_amdgcn_mfma_f32_16x16x32_bf16(qf0, kf0, z, 0, 0, 0);
            z = __builtin_amdgcn_mfma_f32_16x16x32_bf16(qf1, kf1, z, 0, 0, 0);
            s[nt] = z;
        }
        const bool domask = (kv + 63) > wqb;
        float sc[4][4];
#pragma unroll
        for (int nt = 0; nt < 4; ++nt)
#pragma unroll
            for (int r = 0; r < 4; ++r) {
                float v = s[nt][r] * 0.125f;  // H^-0.5
                if (domask) {
                    const int key = kv + 16 * nt + lo;
                    const int row = wqb + 4 * hi + r;
                    if (key > row) v = -1e30f;
                }
                sc[nt][r] = v;
            }
        // online softmax (row lives in 16-lane group)
        float mnew[4], alpha[4], rs[4];
#pragma unroll
        for (int r = 0; r < 4; ++r) {
            float mx = fmaxf(fmaxf(sc[0][r], sc[1][r]), fmaxf(sc[2][r], sc[3][r]));
            mx = fmaxf(mx, __shfl_xor(mx, 1));
            mx = fmaxf(mx, __shfl_xor(mx, 2));
            mx = fmaxf(mx, __shfl_xor(mx, 4));
            mx = fmaxf(mx, __shfl_xor(mx, 8));
            mnew[r] = fmaxf(mrun[r], mx);
            alpha[r] = exp2f((mrun[r] - mnew[r]) * 1.44269504f);
            mrun[r] = mnew[r];
            rs[r] = 0.f;
        }
#pragma unroll
        for (int nt = 0; nt < 4; ++nt)
#pragma unroll
            for (int r = 0; r < 4; ++r) {
                const float p = exp2f((sc[nt][r] - mnew[r]) * 1.44269504f);
                rs[r] += p;
                Plds[wv][4 * hi + r][16 * nt + lo] = f2bf(p);
            }
#pragma unroll
        for (int r = 0; r < 4; ++r) {
            rs[r] += __shfl_xor(rs[r], 1);
            rs[r] += __shfl_xor(rs[r], 2);
            rs[r] += __shfl_xor(rs[r], 4);
            rs[r] += __shfl_xor(rs[r], 8);
            lsum[r] = lsum[r] * alpha[r] + rs[r];
        }
#pragma unroll
        for (int nt = 0; nt < 4; ++nt)
#pragma unroll
            for (int r = 0; r < 4; ++r) o[nt][r] *= alpha[r];
        // PV: O[16 q][64 h] += P[16][64] @ V[64][64]
        const s16x8 pa0 = *reinterpret_cast<const s16x8*>(&Plds[wv][lo][8 * hi]);
        const s16x8 pa1 = *reinterpret_cast<const s16x8*>(&Plds[wv][lo][8 * hi + 32]);
#pragma unroll
        for (int nt = 0; nt < 4; ++nt) {
            const unsigned short* vp = &Vt[((size_t)(b * HH) + 16 * nt + lo) * TT + kv + 8 * hi];
            const s16x8 v0 = *reinterpret_cast<const s16x8*>(vp);
            const s16x8 v1 = *reinterpret_cast<const s16x8*>(vp + 32);
            o[nt] = __builtin_amdgcn_mfma_f32_16x16x32_bf16(pa0, v0, o[nt], 0, 0, 0);
            o[nt] = __builtin_amdgcn_mfma_f32_16x16x32_bf16(pa1, v1, o[nt], 0, 0, 0);
        }
    }
    // ---- combine 8 per-wave partials ----
    __syncthreads();   // everyone done with Plds (aliased below)
#pragma unroll
    for (int nt = 0; nt < 4; ++nt)
#pragma unroll
        for (int r = 0; r < 4; ++r) Of[wv][4 * hi + r][16 * nt + lo] = o[nt][r];
    if (lo == 0) {
#pragma unroll
        for (int r = 0; r < 4; ++r) {
            Mm[wv][4 * hi + r] = mrun[r];
            Ml[wv][4 * hi + r] = lsum[r];
        }
    }
    __syncthreads();
#pragma unroll
    for (int i = 0; i < 2; ++i) {
        const int idx = tid + 512 * i;       // 0..1023
        const int row = idx >> 6, col = idx & 63;
        float M = -1e30f;
#pragma unroll
        for (int s = 0; s < 8; ++s) M = fmaxf(M, Mm[s][row]);
        float accv = 0.f, ltot = 0.f;
#pragma unroll
        for (int s = 0; s < 8; ++s) {
            const float w = exp2f((Mm[s][row] - M) * 1.44269504f);
            accv += w * Of[s][row][col];
            ltot += w * Ml[s][row];
        }
        out[((size_t)(b * TT) + wqb + row) * HH + col] = accv / ltot;
    }
}

extern "C" void kernel_launch(void* const* d_in, const int* in_sizes, int n_in,
                              void* d_out, int out_size, void* d_ws, size_t ws_size,
                              hipStream_t stream) {
    (void)in_sizes; (void)n_in; (void)out_size; (void)ws_size;
    const float* x  = (const float*)d_in[0];
    const float* Wq = (const float*)d_in[1];
    const float* Wk = (const float*)d_in[2];
    const float* Wv = (const float*)d_in[3];
    float* out = (float*)d_out;

    char* ws = (char*)d_ws;
    unsigned short* wT = (unsigned short*)ws;                       // 384 KB
    unsigned short* q  = (unsigned short*)(ws + 393216);            // 2 MB
    unsigned short* k  = (unsigned short*)(ws + 393216 + 2097152);  // 2 MB
    unsigned short* vT = (unsigned short*)(ws + 393216 + 4194304);  // 2 MB

    wt_kernel<<<48, 256, 0, stream>>>(Wq, Wk, Wv, wT);
    qkv_kernel<<<512, 512, 0, stream>>>(x, wT, q, k, vT);
    attn_kernel<<<1024, 512, 0, stream>>>(q, k, vT, out);
}

// Round 3
// 73.348 us; speedup vs baseline: 2.0035x; 1.3857x over previous
//
#include <hip/hip_runtime.h>
#include <hip/hip_bf16.h>

// Problem constants
#define BB 8
#define TT 2048
#define CC 1024
#define HH 64

typedef float f32x4 __attribute__((ext_vector_type(4)));
typedef short s16x8 __attribute__((ext_vector_type(8)));   // 8 bf16 in 4 VGPRs

// fp32 -> bf16 (RNE), pure bit math
static __device__ __forceinline__ unsigned short f2bf(float f) {
    unsigned int u = __float_as_uint(f);
    u = (u + 0x7FFFu + ((u >> 16) & 1u)) >> 16;
    return (unsigned short)u;
}

// ---------------------------------------------------------------------------
// Kernel 0: pack Wq|Wk|Wv [1024][64] fp32 into MFMA B-fragment order, bf16.
// wTf element (((n16*32 + s)*64 + lane)*8 + j) = W^T[n16*16 + (lane&15)]
//   [k = s*32 + 8*(lane>>4) + j]
// so a wave's B-frag load for (n16, k-slot s) is 64 lanes x 16B contiguous.
// ---------------------------------------------------------------------------
__global__ __launch_bounds__(256) void wt_kernel(
    const float* __restrict__ Wq, const float* __restrict__ Wk,
    const float* __restrict__ Wv, unsigned short* __restrict__ wTf) {
    const int e8 = blockIdx.x * 256 + threadIdx.x;  // one frag-slot per thread
    const int lane = e8 & 63;
    const int s = (e8 >> 6) & 31;
    const int n16 = e8 >> 11;        // 0..11
    const int sel = n16 >> 2;
    const float* W = (sel == 0) ? Wq : ((sel == 1) ? Wk : Wv);
    const int h = ((n16 & 3) << 4) + (lane & 15);
    const int cb = s * 32 + ((lane >> 4) << 3);
    s16x8 v;
#pragma unroll
    for (int j = 0; j < 8; ++j) v[j] = (short)f2bf(W[(size_t)(cb + j) * HH + h]);
    *reinterpret_cast<s16x8*>(&wTf[(size_t)e8 * 8]) = v;
}

// ---------------------------------------------------------------------------
// Kernel 1: QKV projection GEMM.  C[16384][192] = X[16384][1024] @ W
// 512 blocks x 8 waves. Block = 32-row M tile, full N=192. BK=128 (8 chunks).
// x chunk: reg-prefetch (issued during prev MFMA) -> cvt bf16 -> swizzled LDS.
// B-frags: coalesced loads from pre-packed wTf (L2-hot).
// ---------------------------------------------------------------------------
__global__ __launch_bounds__(512) void qkv_kernel(
    const float* __restrict__ x, const unsigned short* __restrict__ wTf,
    unsigned short* __restrict__ qo, unsigned short* __restrict__ ko,
    unsigned short* __restrict__ vT) {
    __shared__ unsigned short xb[32 * 128];   // bf16, XOR-swizzled, 8 KB
    const int tid = threadIdx.x;
    const int wv = tid >> 6, lane = tid & 63;
    const int lo = lane & 15, hi = lane >> 4;
    const int wm = wv >> 2, wn = wv & 3;
    const int rb = blockIdx.x * 32;

    // staging assignment: row = tid>>4 (0..31), 8 elems at (tid&15)*8
    const int srow = tid >> 4, sc8 = tid & 15;
    const float* xsrc = &x[(size_t)(rb + srow) * CC + sc8 * 8];
    unsigned short* swr = &xb[srow * 128 + ((sc8 * 8) ^ ((srow & 7) << 3))];

    // A-frag read base (row = wm*16 + lo), swizzled
    const int arow = wm * 16 + lo;
    const int abase = arow * 128;
    const int asw = (arow & 7) << 3;

    f32x4 acc[3];
#pragma unroll
    for (int n = 0; n < 3; ++n) acc[n] = (f32x4){0.f, 0.f, 0.f, 0.f};

    // prefetch chunk 0
    f32x4 pf0 = *reinterpret_cast<const f32x4*>(xsrc);
    f32x4 pf1 = *reinterpret_cast<const f32x4*>(xsrc + 4);

    for (int c = 0; c < 8; ++c) {
        // cvt + LDS write (prefetched regs)
        s16x8 w;
        w[0] = (short)f2bf(pf0[0]); w[1] = (short)f2bf(pf0[1]);
        w[2] = (short)f2bf(pf0[2]); w[3] = (short)f2bf(pf0[3]);
        w[4] = (short)f2bf(pf1[0]); w[5] = (short)f2bf(pf1[1]);
        w[6] = (short)f2bf(pf1[2]); w[7] = (short)f2bf(pf1[3]);
        *reinterpret_cast<s16x8*>(swr) = w;
        __syncthreads();
        // issue next chunk's loads (hide latency under MFMA phase)
        if (c < 7) {
            pf0 = *reinterpret_cast<const f32x4*>(xsrc + (c + 1) * 128);
            pf1 = *reinterpret_cast<const f32x4*>(xsrc + (c + 1) * 128 + 4);
        }
        // A frags from LDS (4 k-halves of 32)
        s16x8 a[4];
#pragma unroll
        for (int kh = 0; kh < 4; ++kh)
            a[kh] = *reinterpret_cast<const s16x8*>(&xb[abase + ((kh * 32 + hi * 8) ^ asw)]);
        // B frags (coalesced from wTf) + MFMA
#pragma unroll
        for (int n = 0; n < 3; ++n) {
            const int n16 = wn * 3 + n;
#pragma unroll
            for (int kh = 0; kh < 4; ++kh) {
                const int slot = c * 4 + kh;
                const s16x8 b = *reinterpret_cast<const s16x8*>(
                    &wTf[(((size_t)n16 * 32 + slot) * 64 + lane) * 8]);
                acc[n] = __builtin_amdgcn_mfma_f32_16x16x32_bf16(a[kh], b, acc[n], 0, 0, 0);
            }
        }
        __syncthreads();   // reads done before next chunk's LDS write
    }

    // Epilogue: C/D layout col=lo, row=4*hi+r
#pragma unroll
    for (int n = 0; n < 3; ++n) {
        const int col = (wn * 3 + n) * 16 + lo;   // 0..191
#pragma unroll
        for (int r = 0; r < 4; ++r) {
            const int row = rb + wm * 16 + 4 * hi + r;
            const unsigned short bv = f2bf(acc[n][r]);
            if (col < 64) {
                qo[(size_t)row * HH + col] = bv;
            } else if (col < 128) {
                ko[(size_t)row * HH + (col - 64)] = bv;
            } else {
                const int bat = row >> 11, t = row & (TT - 1);
                vT[((size_t)(bat * HH + (col - 128))) * TT + t] = bv;
            }
        }
    }
}

// ---------------------------------------------------------------------------
// Kernel 2: flash attention. 1024 blocks (8 batch x 128 q-tiles) x 8 waves.
// (unchanged from round 2)
// ---------------------------------------------------------------------------
__global__ __launch_bounds__(512) void attn_kernel(
    const unsigned short* __restrict__ Q, const unsigned short* __restrict__ K,
    const unsigned short* __restrict__ Vt, float* __restrict__ out) {
    __shared__ __align__(16) char smem[35840];
    unsigned short (*Plds)[16][72] = reinterpret_cast<unsigned short(*)[16][72]>(smem);
    float (*Of)[16][68] = reinterpret_cast<float(*)[16][68]>(smem);
    float (*Mm)[16] = reinterpret_cast<float(*)[16]>(smem + 34816);
    float (*Ml)[16] = reinterpret_cast<float(*)[16]>(smem + 34816 + 512);

    const int tid = threadIdx.x;
    const int wv = tid >> 6, lane = tid & 63;
    const int lo = lane & 15, hi = lane >> 4;
    const int b = blockIdx.x & 7;              // batch -> XCD locality
    const int qt = 127 - (blockIdx.x >> 3);    // largest work first
    const int wqb = qt * 16;

    const unsigned short* qp = &Q[((size_t)(b * TT) + wqb + lo) * HH + 8 * hi];
    const s16x8 qf0 = *reinterpret_cast<const s16x8*>(qp);
    const s16x8 qf1 = *reinterpret_cast<const s16x8*>(qp + 32);

    f32x4 o[4];
#pragma unroll
    for (int nt = 0; nt < 4; ++nt) o[nt] = (f32x4){0.f, 0.f, 0.f, 0.f};
    float mrun[4] = {-1e30f, -1e30f, -1e30f, -1e30f};
    float lsum[4] = {0.f, 0.f, 0.f, 0.f};

    const int ntile = qt / 4 + 1;
    for (int t = wv; t < ntile; t += 8) {
        const int kv = t * 64;
        f32x4 s[4];
#pragma unroll
        for (int nt = 0; nt < 4; ++nt) {
            const unsigned short* kp = &K[((size_t)(b * TT) + kv + 16 * nt + lo) * HH + 8 * hi];
            const s16x8 kf0 = *reinterpret_cast<const s16x8*>(kp);
            const s16x8 kf1 = *reinterpret_cast<const s16x8*>(kp + 32);
            f32x4 z = (f32x4){0.f, 0.f, 0.f, 0.f};
            z = __builtin_amdgcn_mfma_f32_16x16x32_bf16(qf0, kf0, z, 0, 0, 0);
            z = __builtin_amdgcn_mfma_f32_16x16x32_bf16(qf1, kf1, z, 0, 0, 0);
            s[nt] = z;
        }
        const bool domask = (kv + 63) > wqb;
        float sc[4][4];
#pragma unroll
        for (int nt = 0; nt < 4; ++nt)
#pragma unroll
            for (int r = 0; r < 4; ++r) {
                float v = s[nt][r] * 0.125f;
                if (domask) {
                    const int key = kv + 16 * nt + lo;
                    const int row = wqb + 4 * hi + r;
                    if (key > row) v = -1e30f;
                }
                sc[nt][r] = v;
            }
        float mnew[4], alpha[4], rs[4];
#pragma unroll
        for (int r = 0; r < 4; ++r) {
            float mx = fmaxf(fmaxf(sc[0][r], sc[1][r]), fmaxf(sc[2][r], sc[3][r]));
            mx = fmaxf(mx, __shfl_xor(mx, 1));
            mx = fmaxf(mx, __shfl_xor(mx, 2));
            mx = fmaxf(mx, __shfl_xor(mx, 4));
            mx = fmaxf(mx, __shfl_xor(mx, 8));
            mnew[r] = fmaxf(mrun[r], mx);
            alpha[r] = exp2f((mrun[r] - mnew[r]) * 1.44269504f);
            mrun[r] = mnew[r];
            rs[r] = 0.f;
        }
#pragma unroll
        for (int nt = 0; nt < 4; ++nt)
#pragma unroll
            for (int r = 0; r < 4; ++r) {
                const float p = exp2f((sc[nt][r] - mnew[r]) * 1.44269504f);
                rs[r] += p;
                Plds[wv][4 * hi + r][16 * nt + lo] = f2bf(p);
            }
#pragma unroll
        for (int r = 0; r < 4; ++r) {
            rs[r] += __shfl_xor(rs[r], 1);
            rs[r] += __shfl_xor(rs[r], 2);
            rs[r] += __shfl_xor(rs[r], 4);
            rs[r] += __shfl_xor(rs[r], 8);
            lsum[r] = lsum[r] * alpha[r] + rs[r];
        }
#pragma unroll
        for (int nt = 0; nt < 4; ++nt)
#pragma unroll
            for (int r = 0; r < 4; ++r) o[nt][r] *= alpha[r];
        const s16x8 pa0 = *reinterpret_cast<const s16x8*>(&Plds[wv][lo][8 * hi]);
        const s16x8 pa1 = *reinterpret_cast<const s16x8*>(&Plds[wv][lo][8 * hi + 32]);
#pragma unroll
        for (int nt = 0; nt < 4; ++nt) {
            const unsigned short* vp = &Vt[((size_t)(b * HH) + 16 * nt + lo) * TT + kv + 8 * hi];
            const s16x8 v0 = *reinterpret_cast<const s16x8*>(vp);
            const s16x8 v1 = *reinterpret_cast<const s16x8*>(vp + 32);
            o[nt] = __builtin_amdgcn_mfma_f32_16x16x32_bf16(pa0, v0, o[nt], 0, 0, 0);
            o[nt] = __builtin_amdgcn_mfma_f32_16x16x32_bf16(pa1, v1, o[nt], 0, 0, 0);
        }
    }
    // ---- combine 8 per-wave partials ----
    __syncthreads();
#pragma unroll
    for (int nt = 0; nt < 4; ++nt)
#pragma unroll
        for (int r = 0; r < 4; ++r) Of[wv][4 * hi + r][16 * nt + lo] = o[nt][r];
    if (lo == 0) {
#pragma unroll
        for (int r = 0; r < 4; ++r) {
            Mm[wv][4 * hi + r] = mrun[r];
            Ml[wv][4 * hi + r] = lsum[r];
        }
    }
    __syncthreads();
#pragma unroll
    for (int i = 0; i < 2; ++i) {
        const int idx = tid + 512 * i;
        const int row = idx >> 6, col = idx & 63;
        float M = -1e30f;
#pragma unroll
        for (int s = 0; s < 8; ++s) M = fmaxf(M, Mm[s][row]);
        float accv = 0.f, ltot = 0.f;
#pragma unroll
        for (int s = 0; s < 8; ++s) {
            const float w = exp2f((Mm[s][row] - M) * 1.44269504f);
            accv += w * Of[s][row][col];
            ltot += w * Ml[s][row];
        }
        out[((size_t)(b * TT) + wqb + row) * HH + col] = accv / ltot;
    }
}

extern "C" void kernel_launch(void* const* d_in, const int* in_sizes, int n_in,
                              void* d_out, int out_size, void* d_ws, size_t ws_size,
                              hipStream_t stream) {
    (void)in_sizes; (void)n_in; (void)out_size; (void)ws_size;
    const float* x  = (const float*)d_in[0];
    const float* Wq = (const float*)d_in[1];
    const float* Wk = (const float*)d_in[2];
    const float* Wv = (const float*)d_in[3];
    float* out = (float*)d_out;

    char* ws = (char*)d_ws;
    unsigned short* wTf = (unsigned short*)ws;                      // 384 KB
    unsigned short* q   = (unsigned short*)(ws + 393216);           // 2 MB
    unsigned short* k   = (unsigned short*)(ws + 393216 + 2097152); // 2 MB
    unsigned short* vT  = (unsigned short*)(ws + 393216 + 4194304); // 2 MB

    wt_kernel<<<96, 256, 0, stream>>>(Wq, Wk, Wv, wTf);
    qkv_kernel<<<512, 512, 0, stream>>>(x, wTf, q, k, vT);
    attn_kernel<<<1024, 512, 0, stream>>>(q, k, vT, out);
}

// Round 5
// 61.348 us; speedup vs baseline: 2.3954x; 1.1956x over previous
//
#include <hip/hip_runtime.h>
#include <hip/hip_bf16.h>

// Problem constants
#define BB 8
#define TT 2048
#define CC 1024
#define HH 64

typedef float f32x4 __attribute__((ext_vector_type(4)));
typedef float f32x16 __attribute__((ext_vector_type(16)));
typedef short s16x8 __attribute__((ext_vector_type(8)));   // 8 bf16 in 4 VGPRs

// fp32 -> bf16 (RNE), pure bit math
static __device__ __forceinline__ unsigned short f2bf(float f) {
    unsigned int u = __float_as_uint(f);
    u = (u + 0x7FFFu + ((u >> 16) & 1u)) >> 16;
    return (unsigned short)u;
}

// pack two f32 -> 2 bf16 in one dword (RNE); dst.lo = src0, dst.hi = src1
static __device__ __forceinline__ unsigned cvt_pk_bf16(float lo, float hi) {
    unsigned r;
    asm("v_cvt_pk_bf16_f32 %0, %1, %2" : "=v"(r) : "v"(lo), "v"(hi));
    return r;
}

// ---------------------------------------------------------------------------
// Kernel 0: pack Wq|Wk|Wv [1024][64] fp32 into MFMA B-fragment order, bf16.
// ---------------------------------------------------------------------------
__global__ __launch_bounds__(256) void wt_kernel(
    const float* __restrict__ Wq, const float* __restrict__ Wk,
    const float* __restrict__ Wv, unsigned short* __restrict__ wTf) {
    const int e8 = blockIdx.x * 256 + threadIdx.x;
    const int lane = e8 & 63;
    const int s = (e8 >> 6) & 31;
    const int n16 = e8 >> 11;        // 0..11
    const int sel = n16 >> 2;
    const float* W = (sel == 0) ? Wq : ((sel == 1) ? Wk : Wv);
    const int h = ((n16 & 3) << 4) + (lane & 15);
    const int cb = s * 32 + ((lane >> 4) << 3);
    s16x8 v;
#pragma unroll
    for (int j = 0; j < 8; ++j) v[j] = (short)f2bf(W[(size_t)(cb + j) * HH + h]);
    *reinterpret_cast<s16x8*>(&wTf[(size_t)e8 * 8]) = v;
}

// ---------------------------------------------------------------------------
// Kernel 1: QKV projection GEMM (unchanged from round 3, which passed).
// ---------------------------------------------------------------------------
__global__ __launch_bounds__(512) void qkv_kernel(
    const float* __restrict__ x, const unsigned short* __restrict__ wTf,
    unsigned short* __restrict__ qo, unsigned short* __restrict__ ko,
    unsigned short* __restrict__ vT) {
    __shared__ unsigned short xb[32 * 128];
    const int tid = threadIdx.x;
    const int wv = tid >> 6, lane = tid & 63;
    const int lo = lane & 15, hi = lane >> 4;
    const int wm = wv >> 2, wn = wv & 3;
    const int rb = blockIdx.x * 32;

    const int srow = tid >> 4, sc8 = tid & 15;
    const float* xsrc = &x[(size_t)(rb + srow) * CC + sc8 * 8];
    unsigned short* swr = &xb[srow * 128 + ((sc8 * 8) ^ ((srow & 7) << 3))];

    const int arow = wm * 16 + lo;
    const int abase = arow * 128;
    const int asw = (arow & 7) << 3;

    f32x4 acc[3];
#pragma unroll
    for (int n = 0; n < 3; ++n) acc[n] = (f32x4){0.f, 0.f, 0.f, 0.f};

    f32x4 pf0 = *reinterpret_cast<const f32x4*>(xsrc);
    f32x4 pf1 = *reinterpret_cast<const f32x4*>(xsrc + 4);

    for (int c = 0; c < 8; ++c) {
        s16x8 w;
        w[0] = (short)f2bf(pf0[0]); w[1] = (short)f2bf(pf0[1]);
        w[2] = (short)f2bf(pf0[2]); w[3] = (short)f2bf(pf0[3]);
        w[4] = (short)f2bf(pf1[0]); w[5] = (short)f2bf(pf1[1]);
        w[6] = (short)f2bf(pf1[2]); w[7] = (short)f2bf(pf1[3]);
        *reinterpret_cast<s16x8*>(swr) = w;
        __syncthreads();
        if (c < 7) {
            pf0 = *reinterpret_cast<const f32x4*>(xsrc + (c + 1) * 128);
            pf1 = *reinterpret_cast<const f32x4*>(xsrc + (c + 1) * 128 + 4);
        }
        s16x8 a[4];
#pragma unroll
        for (int kh = 0; kh < 4; ++kh)
            a[kh] = *reinterpret_cast<const s16x8*>(&xb[abase + ((kh * 32 + hi * 8) ^ asw)]);
#pragma unroll
        for (int n = 0; n < 3; ++n) {
            const int n16 = wn * 3 + n;
#pragma unroll
            for (int kh = 0; kh < 4; ++kh) {
                const int slot = c * 4 + kh;
                const s16x8 b = *reinterpret_cast<const s16x8*>(
                    &wTf[(((size_t)n16 * 32 + slot) * 64 + lane) * 8]);
                acc[n] = __builtin_amdgcn_mfma_f32_16x16x32_bf16(a[kh], b, acc[n], 0, 0, 0);
            }
        }
        __syncthreads();
    }

#pragma unroll
    for (int n = 0; n < 3; ++n) {
        const int col = (wn * 3 + n) * 16 + lo;
#pragma unroll
        for (int r = 0; r < 4; ++r) {
            const int row = rb + wm * 16 + 4 * hi + r;
            const unsigned short bv = f2bf(acc[n][r]);
            if (col < 64) {
                qo[(size_t)row * HH + col] = bv;
            } else if (col < 128) {
                ko[(size_t)row * HH + (col - 64)] = bv;
            } else {
                const int bat = row >> 11, t = row & (TT - 1);
                vT[((size_t)(bat * HH + (col - 128))) * TT + t] = bv;
            }
        }
    }
}

// ---------------------------------------------------------------------------
// Kernel 2: flash attention, swapped-operand 32x32 form; all cross-lane ops
// via __shfl_xor(,32) (unambiguous semantics).
// 512 blocks (8 batch x 64 q-tiles of 32 rows) x 8 waves, kv tiles strided.
// ---------------------------------------------------------------------------
__global__ __launch_bounds__(512, 4) void attn_kernel(
    const unsigned short* __restrict__ Q, const unsigned short* __restrict__ K,
    const unsigned short* __restrict__ Vt, float* __restrict__ out) {
    __shared__ __align__(16) char smem[33792 + 2048];   // 35.8 KB
    float (*OfL)[64][33] = reinterpret_cast<float(*)[64][33]>(smem);   // 4 slots
    float (*Mm)[32] = reinterpret_cast<float(*)[32]>(smem + 33792);
    float (*Ml)[32] = reinterpret_cast<float(*)[32]>(smem + 33792 + 1024);

    const int tid = threadIdx.x;
    const int wv = tid >> 6, lane = tid & 63;
    const int q = lane & 31, half = lane >> 5;
    const int b = blockIdx.x & 7;              // batch -> XCD L2 locality
    const int qt = 63 - (blockIdx.x >> 3);     // largest work first
    const int qbase = qt * 32;
    const float CEXP = 0.125f * 1.44269504f;   // scale * log2(e)

    // Q B-frags: col = q, element (j, half) <-> k = s*16 + 8*half + j
    const unsigned short* qp = &Q[((size_t)b * TT + qbase + q) * HH + half * 8];
    s16x8 qf[4];
#pragma unroll
    for (int s = 0; s < 4; ++s) qf[s] = *reinterpret_cast<const s16x8*>(qp + s * 16);

    f32x16 oA, oB;   // O^T h-blocks [0..31],[32..63]; lane holds col q
#pragma unroll
    for (int r = 0; r < 16; ++r) { oA[r] = 0.f; oB[r] = 0.f; }
    float m = -1e30f, l = 0.f;   // raw-score domain

    for (int t = wv; t <= qt; t += 8) {
        const int kv = t * 32;
        // V A-frags issued early: row h = q (+32 for oB), elem (j,half) <-> key
        const unsigned short* vbase = &Vt[((size_t)b * HH + q) * TT + kv + half * 8];
        s16x8 vf[4];
#pragma unroll
        for (int mt = 0; mt < 2; ++mt)
#pragma unroll
            for (int s = 0; s < 2; ++s)
                vf[mt * 2 + s] = *reinterpret_cast<const s16x8*>(
                    vbase + (size_t)mt * 32 * TT + s * 16);
        // K A-frags (row = key = q-slot of lane) + QK^T -> S^T[key][q]
        const unsigned short* kp = &K[((size_t)b * TT + kv + q) * HH + half * 8];
        f32x16 sa;
#pragma unroll
        for (int r = 0; r < 16; ++r) sa[r] = 0.f;
#pragma unroll
        for (int s = 0; s < 4; ++s) {
            const s16x8 kf = *reinterpret_cast<const s16x8*>(kp + s * 16);
            sa = __builtin_amdgcn_mfma_f32_32x32x16_bf16(kf, qf[s], sa, 0, 0, 0);
        }
        // causal mask on diagonal tile: key(r) = 4*half + (r&3) + 8*(r>>2)
        if (t == qt) {
#pragma unroll
            for (int r = 0; r < 16; ++r) {
                const int key = 4 * half + (r & 3) + 8 * (r >> 2);
                if (key > q) sa[r] = -1e30f;
            }
        }
        // row max: in-lane tree + partner exchange (keys split across the pair)
        float pmax = sa[0];
#pragma unroll
        for (int r = 1; r < 16; ++r) pmax = fmaxf(pmax, sa[r]);
        pmax = fmaxf(pmax, __shfl_xor(pmax, 32));
        // defer-max: raw thr 64 = 8 in exp units -> P bounded by e^8
        if (!__all(pmax <= m + 64.f)) {
            const float mnew = fmaxf(m, pmax);
            const float alpha = exp2f((m - mnew) * CEXP);
            l *= alpha;
#pragma unroll
            for (int r = 0; r < 16; ++r) { oA[r] *= alpha; oB[r] *= alpha; }
            m = mnew;
        }
        // exp + row sum
        float rs = 0.f;
#pragma unroll
        for (int r = 0; r < 16; ++r) {
            const float p = exp2f((sa[r] - m) * CEXP);
            sa[r] = p;
            rs += p;
        }
        l += rs + __shfl_xor(rs, 32);
        // pack P -> bf16 pairs; redistribute across the pair via shfl_xor(32)
        // lane holds keys: half=0 -> d0..d3 = {0,1|2,3|8,9|10,11}, d4..d7 = {16,17|18,19|24,25|26,27}
        //                  half=1 -> +4 on each pair start
        unsigned d[8], e[8];
#pragma unroll
        for (int i = 0; i < 8; ++i) d[i] = cvt_pk_bf16(sa[2 * i], sa[2 * i + 1]);
#pragma unroll
        for (int i = 0; i < 8; ++i) e[i] = __shfl_xor(d[i], 32);
        union { unsigned u[4]; s16x8 v; } f0, f1;
        f0.u[0] = half ? e[2] : d[0];   // keys  8,9  |  0,1
        f0.u[1] = half ? e[3] : d[1];   // keys 10,11 |  2,3
        f0.u[2] = half ? d[2] : e[0];   // keys 12,13 |  4,5
        f0.u[3] = half ? d[3] : e[1];   // keys 14,15 |  6,7
        f1.u[0] = half ? e[6] : d[4];
        f1.u[1] = half ? e[7] : d[5];
        f1.u[2] = half ? d[6] : e[4];
        f1.u[3] = half ? d[7] : e[5];
        // PV: O^T += V^T @ P^T  (two K=16 steps, two h-blocks)
        oA = __builtin_amdgcn_mfma_f32_32x32x16_bf16(vf[0], f0.v, oA, 0, 0, 0);
        oB = __builtin_amdgcn_mfma_f32_32x32x16_bf16(vf[2], f0.v, oB, 0, 0, 0);
        oA = __builtin_amdgcn_mfma_f32_32x32x16_bf16(vf[1], f1.v, oA, 0, 0, 0);
        oB = __builtin_amdgcn_mfma_f32_32x32x16_bf16(vf[3], f1.v, oB, 0, 0, 0);
    }

    // ---- tree combine of 8 partials ----
#define PUBLISH(slot)                                                      \
    {                                                                      \
        _Pragma("unroll")                                                  \
        for (int r = 0; r < 16; ++r) {                                     \
            const int h0 = (r & 3) + 8 * (r >> 2) + 4 * half;              \
            OfL[slot][h0][q] = oA[r];                                      \
            OfL[slot][h0 + 32][q] = oB[r];                                 \
        }                                                                  \
    }
#define MERGE(slot, srcw)                                                  \
    {                                                                      \
        const float mb = Mm[srcw][q], lb = Ml[srcw][q];                    \
        const float M = fmaxf(m, mb);                                      \
        const float wa = exp2f((m - M) * CEXP);                            \
        const float wb = exp2f((mb - M) * CEXP);                           \
        _Pragma("unroll")                                                  \
        for (int r = 0; r < 16; ++r) {                                     \
            const int h0 = (r & 3) + 8 * (r >> 2) + 4 * half;              \
            oA[r] = oA[r] * wa + OfL[slot][h0][q] * wb;                    \
            oB[r] = oB[r] * wa + OfL[slot][h0 + 32][q] * wb;               \
        }                                                                  \
        l = l * wa + lb * wb;                                              \
        m = M;                                                             \
    }

    if (lane < 32) { Mm[wv][q] = m; Ml[wv][q] = l; }
    if (wv >= 4) PUBLISH(wv - 4);
    __syncthreads();
    if (wv < 4) MERGE(wv, wv + 4);
    __syncthreads();
    if (wv == 2 || wv == 3) {
        PUBLISH(wv - 2);
        if (lane < 32) { Mm[wv][q] = m; Ml[wv][q] = l; }
    }
    __syncthreads();
    if (wv < 2) MERGE(wv, wv + 2);
    __syncthreads();
    if (wv == 1) {
        PUBLISH(1);
        if (lane < 32) { Mm[1][q] = m; Ml[1][q] = l; }
    }
    __syncthreads();
    if (wv == 0) {
        MERGE(1, 1);
        const float inv = 1.f / l;
#pragma unroll
        for (int r = 0; r < 16; ++r) {
            const int h0 = (r & 3) + 8 * (r >> 2) + 4 * half;
            OfL[0][h0][q] = oA[r] * inv;
            OfL[0][h0 + 32][q] = oB[r] * inv;
        }
    }
    __syncthreads();
    // coalesced final write
#pragma unroll
    for (int i = 0; i < 4; ++i) {
        const int idx = tid + 512 * i;
        const int h = idx & 63, q2 = idx >> 6;
        out[((size_t)b * TT + qbase + q2) * HH + h] = OfL[0][h][q2];
    }
#undef PUBLISH
#undef MERGE
}

extern "C" void kernel_launch(void* const* d_in, const int* in_sizes, int n_in,
                              void* d_out, int out_size, void* d_ws, size_t ws_size,
                              hipStream_t stream) {
    (void)in_sizes; (void)n_in; (void)out_size; (void)ws_size;
    const float* x  = (const float*)d_in[0];
    const float* Wq = (const float*)d_in[1];
    const float* Wk = (const float*)d_in[2];
    const float* Wv = (const float*)d_in[3];
    float* out = (float*)d_out;

    char* ws = (char*)d_ws;
    unsigned short* wTf = (unsigned short*)ws;                      // 384 KB
    unsigned short* q   = (unsigned short*)(ws + 393216);           // 2 MB
    unsigned short* k   = (unsigned short*)(ws + 393216 + 2097152); // 2 MB
    unsigned short* vT  = (unsigned short*)(ws + 393216 + 4194304); // 2 MB

    wt_kernel<<<96, 256, 0, stream>>>(Wq, Wk, Wv, wTf);
    qkv_kernel<<<512, 512, 0, stream>>>(x, wTf, q, k, vT);
    attn_kernel<<<512, 512, 0, stream>>>(q, k, vT, out);
}

// Round 6
// 57.733 us; speedup vs baseline: 2.5454x; 1.0626x over previous
//
#include <hip/hip_runtime.h>
#include <hip/hip_bf16.h>

// Problem constants
#define BB 8
#define TT 2048
#define CC 1024
#define HH 64

typedef float f32x4 __attribute__((ext_vector_type(4)));
typedef float f32x16 __attribute__((ext_vector_type(16)));
typedef short s16x8 __attribute__((ext_vector_type(8)));   // 8 bf16 in 4 VGPRs

// fp32 -> bf16 (RNE), pure bit math
static __device__ __forceinline__ unsigned short f2bf(float f) {
    unsigned int u = __float_as_uint(f);
    u = (u + 0x7FFFu + ((u >> 16) & 1u)) >> 16;
    return (unsigned short)u;
}

// pack two f32 -> 2 bf16 in one dword (RNE); dst.lo = src0, dst.hi = src1
static __device__ __forceinline__ unsigned cvt_pk_bf16(float lo, float hi) {
    unsigned r;
    asm("v_cvt_pk_bf16_f32 %0, %1, %2" : "=v"(r) : "v"(lo), "v"(hi));
    return r;
}

// ---------------------------------------------------------------------------
// Kernel 0: pack Wq|Wk|Wv [1024][64] fp32 into MFMA B-fragment order, bf16.
// wTf[(((n16*32+s)*64+lane)*8+j)] = W^T[n16*16+(lane&15)][s*32+8*(lane>>4)+j]
// ---------------------------------------------------------------------------
__global__ __launch_bounds__(256) void wt_kernel(
    const float* __restrict__ Wq, const float* __restrict__ Wk,
    const float* __restrict__ Wv, unsigned short* __restrict__ wTf) {
    const int e8 = blockIdx.x * 256 + threadIdx.x;
    const int lane = e8 & 63;
    const int s = (e8 >> 6) & 31;
    const int n16 = e8 >> 11;        // 0..11
    const int sel = n16 >> 2;
    const float* W = (sel == 0) ? Wq : ((sel == 1) ? Wk : Wv);
    const int h = ((n16 & 3) << 4) + (lane & 15);
    const int cb = s * 32 + ((lane >> 4) << 3);
    s16x8 v;
#pragma unroll
    for (int j = 0; j < 8; ++j) v[j] = (short)f2bf(W[(size_t)(cb + j) * HH + h]);
    *reinterpret_cast<s16x8*>(&wTf[(size_t)e8 * 8]) = v;
}

// ---------------------------------------------------------------------------
// Kernel 1: QKV projection GEMM v2.  C[16384][192] = X[16384][1024] @ W
// 256 blocks x 8 waves; block = 64 rows. Wave (wm,wn): 32 rows (2 M-frags,
// B-frags reused across both -> wTf L2 traffic halved to 192 MB) x 48 cols.
// BK=128, 8 chunks, dbuf LDS, ONE barrier/chunk, reg-prefetch x, 2-ahead
// B-register pipeline (fully unrolled -> static indexing).
// ---------------------------------------------------------------------------
__global__ __launch_bounds__(512, 2) void qkv_kernel(
    const float* __restrict__ x, const unsigned short* __restrict__ wTf,
    unsigned short* __restrict__ qo, unsigned short* __restrict__ ko,
    unsigned short* __restrict__ vT) {
    __shared__ unsigned short xb[2][64 * 128];   // 2 x 16 KB bf16, XOR-swizzled
    const int tid = threadIdx.x;
    const int wv = tid >> 6, lane = tid & 63;
    const int lo = lane & 15, hi = lane >> 4;
    const int wm = wv >> 2, wn = wv & 3;
    const int rb = blockIdx.x * 64;

    // staging: thread covers row = tid>>3 (0..63), 16 f32 at col (tid&7)*16
    const int srow = tid >> 3, sc = (tid & 7) * 16;
    const float* xsrc = &x[(size_t)(rb + srow) * CC + sc];
    const int swz = (srow & 7) << 3;
    const int wg0 = srow * 128 + (sc ^ swz);        // granule elem offsets
    const int wg1 = srow * 128 + ((sc + 8) ^ swz);

    // A-frag read bases: rows wm*32 + {0,16} + lo
    const int ar0 = (wm * 32 + lo) * 128;
    const int ar1 = ar0 + 16 * 128;
    const int aswz = (lo & 7) << 3;

    f32x4 acc[2][3];
#pragma unroll
    for (int m = 0; m < 2; ++m)
#pragma unroll
        for (int n = 0; n < 3; ++n) acc[m][n] = (f32x4){0.f, 0.f, 0.f, 0.f};

    // prefetch x chunk 0
    f32x4 pf[4];
#pragma unroll
    for (int i = 0; i < 4; ++i) pf[i] = *reinterpret_cast<const f32x4*>(xsrc + 4 * i);

    // B pipeline: 3 reg sets over 32 slots (slot s -> set s%3), 2-ahead
    s16x8 bv[3][3];
#define BLOAD(SET, SLOT)                                                       \
    {                                                                          \
        _Pragma("unroll")                                                      \
        for (int n = 0; n < 3; ++n)                                            \
            bv[SET][n] = *reinterpret_cast<const s16x8*>(                      \
                &wTf[(((size_t)(wn * 3 + n) * 32 + (SLOT)) * 64 + lane) * 8]); \
    }
    BLOAD(0, 0)
    BLOAD(1, 1)

#pragma unroll
    for (int c = 0; c < 8; ++c) {
        // write staged chunk c (from pf regs) into xb[c&1]
        unsigned short* wb = xb[c & 1];
        s16x8 w0, w1;
        w0[0] = (short)f2bf(pf[0][0]); w0[1] = (short)f2bf(pf[0][1]);
        w0[2] = (short)f2bf(pf[0][2]); w0[3] = (short)f2bf(pf[0][3]);
        w0[4] = (short)f2bf(pf[1][0]); w0[5] = (short)f2bf(pf[1][1]);
        w0[6] = (short)f2bf(pf[1][2]); w0[7] = (short)f2bf(pf[1][3]);
        w1[0] = (short)f2bf(pf[2][0]); w1[1] = (short)f2bf(pf[2][1]);
        w1[2] = (short)f2bf(pf[2][2]); w1[3] = (short)f2bf(pf[2][3]);
        w1[4] = (short)f2bf(pf[3][0]); w1[5] = (short)f2bf(pf[3][1]);
        w1[6] = (short)f2bf(pf[3][2]); w1[7] = (short)f2bf(pf[3][3]);
        *reinterpret_cast<s16x8*>(&wb[wg0]) = w0;
        *reinterpret_cast<s16x8*>(&wb[wg1]) = w1;
        __syncthreads();
        // issue next chunk's x loads (land during this chunk's compute)
        if (c < 7) {
#pragma unroll
            for (int i = 0; i < 4; ++i)
                pf[i] = *reinterpret_cast<const f32x4*>(xsrc + (c + 1) * 128 + 4 * i);
        }
        const unsigned short* base = xb[c & 1];
#pragma unroll
        for (int kh = 0; kh < 4; ++kh) {
            const int slot = c * 4 + kh;
            if (slot + 2 < 32) BLOAD((slot + 2) % 3, slot + 2)
            const s16x8 a0 = *reinterpret_cast<const s16x8*>(
                &base[ar0 + ((kh * 32 + hi * 8) ^ aswz)]);
            const s16x8 a1 = *reinterpret_cast<const s16x8*>(
                &base[ar1 + ((kh * 32 + hi * 8) ^ aswz)]);
#pragma unroll
            for (int n = 0; n < 3; ++n) {
                acc[0][n] = __builtin_amdgcn_mfma_f32_16x16x32_bf16(a0, bv[slot % 3][n], acc[0][n], 0, 0, 0);
                acc[1][n] = __builtin_amdgcn_mfma_f32_16x16x32_bf16(a1, bv[slot % 3][n], acc[1][n], 0, 0, 0);
            }
        }
    }
#undef BLOAD

    // Epilogue: C/D layout col=lo, row=4*hi+r
#pragma unroll
    for (int n = 0; n < 3; ++n) {
        const int col = (wn * 3 + n) * 16 + lo;   // 0..191
#pragma unroll
        for (int m = 0; m < 2; ++m) {
#pragma unroll
            for (int r = 0; r < 4; ++r) {
                const int row = rb + wm * 32 + m * 16 + 4 * hi + r;
                const unsigned short bvv = f2bf(acc[m][n][r]);
                if (col < 64) {
                    qo[(size_t)row * HH + col] = bvv;
                } else if (col < 128) {
                    ko[(size_t)row * HH + (col - 64)] = bvv;
                } else {
                    const int bat = row >> 11, t = row & (TT - 1);
                    vT[((size_t)(bat * HH + (col - 128))) * TT + t] = bvv;
                }
            }
        }
    }
}

// ---------------------------------------------------------------------------
// Kernel 2: flash attention, swapped-operand 32x32 form (reg-diet rev).
// 512 blocks (8 batch x 64 q-tiles of 32 rows) x 8 waves, kv tiles strided.
// P-redistribution now 4 shfls (send/recv) instead of 8.
// ---------------------------------------------------------------------------
__global__ __launch_bounds__(512, 4) void attn_kernel(
    const unsigned short* __restrict__ Q, const unsigned short* __restrict__ K,
    const unsigned short* __restrict__ Vt, float* __restrict__ out) {
    __shared__ __align__(16) char smem[33792 + 2048];   // 35.8 KB
    float (*OfL)[64][33] = reinterpret_cast<float(*)[64][33]>(smem);   // 4 slots
    float (*Mm)[32] = reinterpret_cast<float(*)[32]>(smem + 33792);
    float (*Ml)[32] = reinterpret_cast<float(*)[32]>(smem + 33792 + 1024);

    const int tid = threadIdx.x;
    const int wv = tid >> 6, lane = tid & 63;
    const int q = lane & 31, half = lane >> 5;
    const int b = blockIdx.x & 7;              // batch -> XCD L2 locality
    const int qt = 63 - (blockIdx.x >> 3);     // largest work first
    const int qbase = qt * 32;
    const float CEXP = 0.125f * 1.44269504f;   // scale * log2(e)

    // Q B-frags: col = q, element (j, half) <-> k = s*16 + 8*half + j
    const unsigned short* qp = &Q[((size_t)b * TT + qbase + q) * HH + half * 8];
    s16x8 qf[4];
#pragma unroll
    for (int s = 0; s < 4; ++s) qf[s] = *reinterpret_cast<const s16x8*>(qp + s * 16);

    f32x16 oA, oB;   // O^T h-blocks [0..31],[32..63]; lane holds col q
#pragma unroll
    for (int r = 0; r < 16; ++r) { oA[r] = 0.f; oB[r] = 0.f; }
    float m = -1e30f, l = 0.f;   // raw-score domain

    for (int t = wv; t <= qt; t += 8) {
        const int kv = t * 32;
        // V A-frags issued early: row h = q (+32 for oB), elem (j,half) <-> key
        const unsigned short* vbase = &Vt[((size_t)b * HH + q) * TT + kv + half * 8];
        s16x8 vf[4];
#pragma unroll
        for (int mt = 0; mt < 2; ++mt)
#pragma unroll
            for (int s = 0; s < 2; ++s)
                vf[mt * 2 + s] = *reinterpret_cast<const s16x8*>(
                    vbase + (size_t)mt * 32 * TT + s * 16);
        // K A-frags (row = key) + QK^T -> S^T[key][q]
        const unsigned short* kp = &K[((size_t)b * TT + kv + q) * HH + half * 8];
        f32x16 sa;
#pragma unroll
        for (int r = 0; r < 16; ++r) sa[r] = 0.f;
#pragma unroll
        for (int s = 0; s < 4; ++s) {
            const s16x8 kf = *reinterpret_cast<const s16x8*>(kp + s * 16);
            sa = __builtin_amdgcn_mfma_f32_32x32x16_bf16(kf, qf[s], sa, 0, 0, 0);
        }
        // causal mask on diagonal tile: key(r) = 4*half + (r&3) + 8*(r>>2)
        if (t == qt) {
#pragma unroll
            for (int r = 0; r < 16; ++r) {
                const int key = 4 * half + (r & 3) + 8 * (r >> 2);
                if (key > q) sa[r] = -1e30f;
            }
        }
        // row max: in-lane tree + partner exchange
        float pmax = sa[0];
#pragma unroll
        for (int r = 1; r < 16; ++r) pmax = fmaxf(pmax, sa[r]);
        pmax = fmaxf(pmax, __shfl_xor(pmax, 32));
        // defer-max: raw thr 64 = 8 in exp units -> P bounded by e^8
        if (!__all(pmax <= m + 64.f)) {
            const float mnew = fmaxf(m, pmax);
            const float alpha = exp2f((m - mnew) * CEXP);
            l *= alpha;
#pragma unroll
            for (int r = 0; r < 16; ++r) { oA[r] *= alpha; oB[r] *= alpha; }
            m = mnew;
        }
        // exp + row sum
        float rs = 0.f;
#pragma unroll
        for (int r = 0; r < 16; ++r) {
            const float p = exp2f((sa[r] - m) * CEXP);
            sa[r] = p;
            rs += p;
        }
        l += rs + __shfl_xor(rs, 32);
        // pack P -> bf16 pairs; exchange only the 4 words the partner needs
        unsigned d[8];
#pragma unroll
        for (int i = 0; i < 8; ++i) d[i] = cvt_pk_bf16(sa[2 * i], sa[2 * i + 1]);
        const unsigned snd0 = half ? d[0] : d[2];
        const unsigned snd1 = half ? d[1] : d[3];
        const unsigned snd2 = half ? d[4] : d[6];
        const unsigned snd3 = half ? d[5] : d[7];
        const unsigned rcv0 = __shfl_xor(snd0, 32);
        const unsigned rcv1 = __shfl_xor(snd1, 32);
        const unsigned rcv2 = __shfl_xor(snd2, 32);
        const unsigned rcv3 = __shfl_xor(snd3, 32);
        union { unsigned u[4]; s16x8 v; } f0, f1;
        f0.u[0] = half ? rcv0 : d[0];
        f0.u[1] = half ? rcv1 : d[1];
        f0.u[2] = half ? d[2] : rcv0;
        f0.u[3] = half ? d[3] : rcv1;
        f1.u[0] = half ? rcv2 : d[4];
        f1.u[1] = half ? rcv3 : d[5];
        f1.u[2] = half ? d[6] : rcv2;
        f1.u[3] = half ? d[7] : rcv3;
        // PV: O^T += V^T @ P^T  (two K=16 steps, two h-blocks)
        oA = __builtin_amdgcn_mfma_f32_32x32x16_bf16(vf[0], f0.v, oA, 0, 0, 0);
        oB = __builtin_amdgcn_mfma_f32_32x32x16_bf16(vf[2], f0.v, oB, 0, 0, 0);
        oA = __builtin_amdgcn_mfma_f32_32x32x16_bf16(vf[1], f1.v, oA, 0, 0, 0);
        oB = __builtin_amdgcn_mfma_f32_32x32x16_bf16(vf[3], f1.v, oB, 0, 0, 0);
    }

    // ---- tree combine of 8 partials ----
#define PUBLISH(slot)                                                      \
    {                                                                      \
        _Pragma("unroll")                                                  \
        for (int r = 0; r < 16; ++r) {                                     \
            const int h0 = (r & 3) + 8 * (r >> 2) + 4 * half;              \
            OfL[slot][h0][q] = oA[r];                                      \
            OfL[slot][h0 + 32][q] = oB[r];                                 \
        }                                                                  \
    }
#define MERGE(slot, srcw)                                                  \
    {                                                                      \
        const float mb = Mm[srcw][q], lb = Ml[srcw][q];                    \
        const float M = fmaxf(m, mb);                                      \
        const float wa = exp2f((m - M) * CEXP);                            \
        const float wb = exp2f((mb - M) * CEXP);                           \
        _Pragma("unroll")                                                  \
        for (int r = 0; r < 16; ++r) {                                     \
            const int h0 = (r & 3) + 8 * (r >> 2) + 4 * half;              \
            oA[r] = oA[r] * wa + OfL[slot][h0][q] * wb;                    \
            oB[r] = oB[r] * wa + OfL[slot][h0 + 32][q] * wb;               \
        }                                                                  \
        l = l * wa + lb * wb;                                              \
        m = M;                                                             \
    }

    if (lane < 32) { Mm[wv][q] = m; Ml[wv][q] = l; }
    if (wv >= 4) PUBLISH(wv - 4);
    __syncthreads();
    if (wv < 4) MERGE(wv, wv + 4);
    __syncthreads();
    if (wv == 2 || wv == 3) {
        PUBLISH(wv - 2);
        if (lane < 32) { Mm[wv][q] = m; Ml[wv][q] = l; }
    }
    __syncthreads();
    if (wv < 2) MERGE(wv, wv + 2);
    __syncthreads();
    if (wv == 1) {
        PUBLISH(1);
        if (lane < 32) { Mm[1][q] = m; Ml[1][q] = l; }
    }
    __syncthreads();
    if (wv == 0) {
        MERGE(1, 1);
        const float inv = 1.f / l;
#pragma unroll
        for (int r = 0; r < 16; ++r) {
            const int h0 = (r & 3) + 8 * (r >> 2) + 4 * half;
            OfL[0][h0][q] = oA[r] * inv;
            OfL[0][h0 + 32][q] = oB[r] * inv;
        }
    }
    __syncthreads();
    // coalesced final write
#pragma unroll
    for (int i = 0; i < 4; ++i) {
        const int idx = tid + 512 * i;
        const int h = idx & 63, q2 = idx >> 6;
        out[((size_t)b * TT + qbase + q2) * HH + h] = OfL[0][h][q2];
    }
#undef PUBLISH
#undef MERGE
}

extern "C" void kernel_launch(void* const* d_in, const int* in_sizes, int n_in,
                              void* d_out, int out_size, void* d_ws, size_t ws_size,
                              hipStream_t stream) {
    (void)in_sizes; (void)n_in; (void)out_size; (void)ws_size;
    const float* x  = (const float*)d_in[0];
    const float* Wq = (const float*)d_in[1];
    const float* Wk = (const float*)d_in[2];
    const float* Wv = (const float*)d_in[3];
    float* out = (float*)d_out;

    char* ws = (char*)d_ws;
    unsigned short* wTf = (unsigned short*)ws;                      // 384 KB
    unsigned short* q   = (unsigned short*)(ws + 393216);           // 2 MB
    unsigned short* k   = (unsigned short*)(ws + 393216 + 2097152); // 2 MB
    unsigned short* vT  = (unsigned short*)(ws + 393216 + 4194304); // 2 MB

    wt_kernel<<<96, 256, 0, stream>>>(Wq, Wk, Wv, wTf);
    qkv_kernel<<<256, 512, 0, stream>>>(x, wTf, q, k, vT);
    attn_kernel<<<512, 512, 0, stream>>>(q, k, vT, out);
}

// Round 7
// 45.418 us; speedup vs baseline: 3.2356x; 1.2711x over previous
//
#include <hip/hip_runtime.h>
#include <hip/hip_bf16.h>

// Problem constants
#define BB 8
#define TT 2048
#define CC 1024
#define HH 64

typedef float f32x4 __attribute__((ext_vector_type(4)));
typedef float f32x16 __attribute__((ext_vector_type(16)));
typedef short s16x8 __attribute__((ext_vector_type(8)));   // 8 bf16 in 4 VGPRs

// fp32 -> bf16 (RNE), pure bit math
static __device__ __forceinline__ unsigned short f2bf(float f) {
    unsigned int u = __float_as_uint(f);
    u = (u + 0x7FFFu + ((u >> 16) & 1u)) >> 16;
    return (unsigned short)u;
}

// pack two f32 -> 2 bf16 in one dword (RNE); dst.lo = src0, dst.hi = src1
static __device__ __forceinline__ unsigned cvt_pk_bf16(float lo, float hi) {
    unsigned r;
    asm("v_cvt_pk_bf16_f32 %0, %1, %2" : "=v"(r) : "v"(lo), "v"(hi));
    return r;
}

// ---------------------------------------------------------------------------
// Kernel 0: pack Wq|Wk|Wv [1024][64] fp32 into MFMA B-fragment order, bf16.
// ---------------------------------------------------------------------------
__global__ __launch_bounds__(256) void wt_kernel(
    const float* __restrict__ Wq, const float* __restrict__ Wk,
    const float* __restrict__ Wv, unsigned short* __restrict__ wTf) {
    const int e8 = blockIdx.x * 256 + threadIdx.x;
    const int lane = e8 & 63;
    const int s = (e8 >> 6) & 31;
    const int n16 = e8 >> 11;        // 0..11
    const int sel = n16 >> 2;
    const float* W = (sel == 0) ? Wq : ((sel == 1) ? Wk : Wv);
    const int h = ((n16 & 3) << 4) + (lane & 15);
    const int cb = s * 32 + ((lane >> 4) << 3);
    s16x8 v;
#pragma unroll
    for (int j = 0; j < 8; ++j) v[j] = (short)f2bf(W[(size_t)(cb + j) * HH + h]);
    *reinterpret_cast<s16x8*>(&wTf[(size_t)e8 * 8]) = v;
}

// ---------------------------------------------------------------------------
// Kernel 1: QKV projection GEMM v3.  Same mainloop as v2; epilogue now emits
// Q/K/V in 32x32-MFMA FRAGMENT order so attn loads are 64-lane contiguous:
//  Qf/Kf[(((b*64+tile)*4 + s)*64 + half*32 + row32)*8 + j]
//     = Q/K[b][tile*32+row32][s*16 + 8*half + j]
//  Vf[((((b*64+tile)*2+mt)*2 + s)*64 + half*32 + h32)*8 + j]
//     = V[b][tile*32 + s*16 + 8*half + j][mt*32 + h32]   (V^T fragment)
// ---------------------------------------------------------------------------
__global__ __launch_bounds__(512, 2) void qkv_kernel(
    const float* __restrict__ x, const unsigned short* __restrict__ wTf,
    unsigned short* __restrict__ Qf, unsigned short* __restrict__ Kf,
    unsigned short* __restrict__ Vf) {
    __shared__ unsigned short xb[2][64 * 128];   // 2 x 16 KB bf16, XOR-swizzled
    const int tid = threadIdx.x;
    const int wv = tid >> 6, lane = tid & 63;
    const int lo = lane & 15, hi = lane >> 4;
    const int wm = wv >> 2, wn = wv & 3;
    const int rb = blockIdx.x * 64;

    const int srow = tid >> 3, sc = (tid & 7) * 16;
    const float* xsrc = &x[(size_t)(rb + srow) * CC + sc];
    const int swz = (srow & 7) << 3;
    const int wg0 = srow * 128 + (sc ^ swz);
    const int wg1 = srow * 128 + ((sc + 8) ^ swz);

    const int ar0 = (wm * 32 + lo) * 128;
    const int ar1 = ar0 + 16 * 128;
    const int aswz = (lo & 7) << 3;

    f32x4 acc[2][3];
#pragma unroll
    for (int m = 0; m < 2; ++m)
#pragma unroll
        for (int n = 0; n < 3; ++n) acc[m][n] = (f32x4){0.f, 0.f, 0.f, 0.f};

    f32x4 pf[4];
#pragma unroll
    for (int i = 0; i < 4; ++i) pf[i] = *reinterpret_cast<const f32x4*>(xsrc + 4 * i);

    s16x8 bv[3][3];
#define BLOAD(SET, SLOT)                                                       \
    {                                                                          \
        _Pragma("unroll")                                                      \
        for (int n = 0; n < 3; ++n)                                            \
            bv[SET][n] = *reinterpret_cast<const s16x8*>(                      \
                &wTf[(((size_t)(wn * 3 + n) * 32 + (SLOT)) * 64 + lane) * 8]); \
    }
    BLOAD(0, 0)
    BLOAD(1, 1)

#pragma unroll
    for (int c = 0; c < 8; ++c) {
        unsigned short* wb = xb[c & 1];
        s16x8 w0, w1;
        w0[0] = (short)f2bf(pf[0][0]); w0[1] = (short)f2bf(pf[0][1]);
        w0[2] = (short)f2bf(pf[0][2]); w0[3] = (short)f2bf(pf[0][3]);
        w0[4] = (short)f2bf(pf[1][0]); w0[5] = (short)f2bf(pf[1][1]);
        w0[6] = (short)f2bf(pf[1][2]); w0[7] = (short)f2bf(pf[1][3]);
        w1[0] = (short)f2bf(pf[2][0]); w1[1] = (short)f2bf(pf[2][1]);
        w1[2] = (short)f2bf(pf[2][2]); w1[3] = (short)f2bf(pf[2][3]);
        w1[4] = (short)f2bf(pf[3][0]); w1[5] = (short)f2bf(pf[3][1]);
        w1[6] = (short)f2bf(pf[3][2]); w1[7] = (short)f2bf(pf[3][3]);
        *reinterpret_cast<s16x8*>(&wb[wg0]) = w0;
        *reinterpret_cast<s16x8*>(&wb[wg1]) = w1;
        __syncthreads();
        if (c < 7) {
#pragma unroll
            for (int i = 0; i < 4; ++i)
                pf[i] = *reinterpret_cast<const f32x4*>(xsrc + (c + 1) * 128 + 4 * i);
        }
        const unsigned short* base = xb[c & 1];
#pragma unroll
        for (int kh = 0; kh < 4; ++kh) {
            const int slot = c * 4 + kh;
            if (slot + 2 < 32) BLOAD((slot + 2) % 3, slot + 2)
            const s16x8 a0 = *reinterpret_cast<const s16x8*>(
                &base[ar0 + ((kh * 32 + hi * 8) ^ aswz)]);
            const s16x8 a1 = *reinterpret_cast<const s16x8*>(
                &base[ar1 + ((kh * 32 + hi * 8) ^ aswz)]);
#pragma unroll
            for (int n = 0; n < 3; ++n) {
                acc[0][n] = __builtin_amdgcn_mfma_f32_16x16x32_bf16(a0, bv[slot % 3][n], acc[0][n], 0, 0, 0);
                acc[1][n] = __builtin_amdgcn_mfma_f32_16x16x32_bf16(a1, bv[slot % 3][n], acc[1][n], 0, 0, 0);
            }
        }
    }
#undef BLOAD

    // Epilogue -> fragment layouts. C/D: col=16*n16+lo, row=rb+wm*32+m*16+4*hi+r
#pragma unroll
    for (int n = 0; n < 3; ++n) {
        const int n16 = wn * 3 + n;
        const int sel = n16 >> 2;
#pragma unroll
        for (int m = 0; m < 2; ++m) {
#pragma unroll
            for (int r = 0; r < 4; ++r) {
                const int row = rb + wm * 32 + m * 16 + 4 * hi + r;
                const int b_ = row >> 11, tok = row & (TT - 1);
                const int tile = tok >> 5;
                const unsigned short bvv = f2bf(acc[m][n][r]);
                if (sel == 0) {
                    const int s = n16, half = (lo >> 3) & 1, j = lo & 7;
                    Qf[((((size_t)b_ * 64 + tile) * 4 + s) * 64 + half * 32 + (tok & 31)) * 8 + j] = bvv;
                } else if (sel == 1) {
                    const int s = n16 - 4, half = (lo >> 3) & 1, j = lo & 7;
                    Kf[((((size_t)b_ * 64 + tile) * 4 + s) * 64 + half * 32 + (tok & 31)) * 8 + j] = bvv;
                } else {
                    const int h = (n16 - 8) * 16 + lo;
                    const int mt = h >> 5;
                    const int tt = tok & 31;
                    const int s2 = tt >> 4, hf = (tt >> 3) & 1, jj = tt & 7;
                    Vf[(((((size_t)b_ * 64 + tile) * 2 + mt) * 2 + s2) * 64 + hf * 32 + (h & 31)) * 8 + jj] = bvv;
                }
            }
        }
    }
}

// ---------------------------------------------------------------------------
// Kernel 2: flash attention, swapped-operand 32x32 form; all operand loads
// are now 64-lane contiguous 1KB fragment reads (no cache-line splits).
// 512 blocks (8 batch x 64 q-tiles of 32 rows) x 8 waves, kv tiles strided.
// ---------------------------------------------------------------------------
__global__ __launch_bounds__(512, 4) void attn_kernel(
    const unsigned short* __restrict__ Qf, const unsigned short* __restrict__ Kf,
    const unsigned short* __restrict__ Vf, float* __restrict__ out) {
    __shared__ __align__(16) char smem[33792 + 2048];   // 35.8 KB
    float (*OfL)[64][33] = reinterpret_cast<float(*)[64][33]>(smem);   // 4 slots
    float (*Mm)[32] = reinterpret_cast<float(*)[32]>(smem + 33792);
    float (*Ml)[32] = reinterpret_cast<float(*)[32]>(smem + 33792 + 1024);

    const int tid = threadIdx.x;
    const int wv = tid >> 6, lane = tid & 63;
    const int q = lane & 31, half = lane >> 5;
    const int b = blockIdx.x & 7;              // batch -> XCD L2 locality
    const int qt = 63 - (blockIdx.x >> 3);     // largest work first
    const int qbase = qt * 32;
    const float CEXP = 0.125f * 1.44269504f;   // scale * log2(e)

    // Q fragments: one 1KB coalesced load per s
    const unsigned short* qp = &Qf[(((size_t)b * 64 + qt) * 256 + lane) * 8];
    s16x8 qf[4];
#pragma unroll
    for (int s = 0; s < 4; ++s) qf[s] = *reinterpret_cast<const s16x8*>(qp + s * 512);

    f32x16 oA, oB;   // O^T h-blocks [0..31],[32..63]; lane holds col q
#pragma unroll
    for (int r = 0; r < 16; ++r) { oA[r] = 0.f; oB[r] = 0.f; }
    float m = -1e30f, l = 0.f;   // raw-score domain

    for (int t = wv; t <= qt; t += 8) {
        // V fragments (issued early, contiguous)
        const unsigned short* vp = &Vf[(((size_t)b * 64 + t) * 256 + lane) * 8];
        s16x8 vf[4];
#pragma unroll
        for (int i = 0; i < 4; ++i)
            vf[i] = *reinterpret_cast<const s16x8*>(vp + i * 512);
        // K fragments + QK^T -> S^T[key][q]
        const unsigned short* kp = &Kf[(((size_t)b * 64 + t) * 256 + lane) * 8];
        f32x16 sa;
#pragma unroll
        for (int r = 0; r < 16; ++r) sa[r] = 0.f;
#pragma unroll
        for (int s = 0; s < 4; ++s) {
            const s16x8 kf = *reinterpret_cast<const s16x8*>(kp + s * 512);
            sa = __builtin_amdgcn_mfma_f32_32x32x16_bf16(kf, qf[s], sa, 0, 0, 0);
        }
        // causal mask on diagonal tile: key(r) = 4*half + (r&3) + 8*(r>>2)
        if (t == qt) {
#pragma unroll
            for (int r = 0; r < 16; ++r) {
                const int key = 4 * half + (r & 3) + 8 * (r >> 2);
                if (key > q) sa[r] = -1e30f;
            }
        }
        // row max: in-lane tree + partner exchange
        float pmax = sa[0];
#pragma unroll
        for (int r = 1; r < 16; ++r) pmax = fmaxf(pmax, sa[r]);
        pmax = fmaxf(pmax, __shfl_xor(pmax, 32));
        // defer-max: raw thr 64 = 8 in exp units -> P bounded by e^8
        if (!__all(pmax <= m + 64.f)) {
            const float mnew = fmaxf(m, pmax);
            const float alpha = exp2f((m - mnew) * CEXP);
            l *= alpha;
#pragma unroll
            for (int r = 0; r < 16; ++r) { oA[r] *= alpha; oB[r] *= alpha; }
            m = mnew;
        }
        // exp + row sum
        float rs = 0.f;
#pragma unroll
        for (int r = 0; r < 16; ++r) {
            const float p = exp2f((sa[r] - m) * CEXP);
            sa[r] = p;
            rs += p;
        }
        l += rs + __shfl_xor(rs, 32);
        // pack P -> bf16 pairs; exchange only the 4 words the partner needs
        unsigned d[8];
#pragma unroll
        for (int i = 0; i < 8; ++i) d[i] = cvt_pk_bf16(sa[2 * i], sa[2 * i + 1]);
        const unsigned snd0 = half ? d[0] : d[2];
        const unsigned snd1 = half ? d[1] : d[3];
        const unsigned snd2 = half ? d[4] : d[6];
        const unsigned snd3 = half ? d[5] : d[7];
        const unsigned rcv0 = __shfl_xor(snd0, 32);
        const unsigned rcv1 = __shfl_xor(snd1, 32);
        const unsigned rcv2 = __shfl_xor(snd2, 32);
        const unsigned rcv3 = __shfl_xor(snd3, 32);
        union { unsigned u[4]; s16x8 v; } f0, f1;
        f0.u[0] = half ? rcv0 : d[0];
        f0.u[1] = half ? rcv1 : d[1];
        f0.u[2] = half ? d[2] : rcv0;
        f0.u[3] = half ? d[3] : rcv1;
        f1.u[0] = half ? rcv2 : d[4];
        f1.u[1] = half ? rcv3 : d[5];
        f1.u[2] = half ? d[6] : rcv2;
        f1.u[3] = half ? d[7] : rcv3;
        // PV: O^T += V^T @ P^T  (two K=16 steps, two h-blocks)
        oA = __builtin_amdgcn_mfma_f32_32x32x16_bf16(vf[0], f0.v, oA, 0, 0, 0);
        oB = __builtin_amdgcn_mfma_f32_32x32x16_bf16(vf[2], f0.v, oB, 0, 0, 0);
        oA = __builtin_amdgcn_mfma_f32_32x32x16_bf16(vf[1], f1.v, oA, 0, 0, 0);
        oB = __builtin_amdgcn_mfma_f32_32x32x16_bf16(vf[3], f1.v, oB, 0, 0, 0);
    }

    // ---- tree combine of 8 partials ----
#define PUBLISH(slot)                                                      \
    {                                                                      \
        _Pragma("unroll")                                                  \
        for (int r = 0; r < 16; ++r) {                                     \
            const int h0 = (r & 3) + 8 * (r >> 2) + 4 * half;              \
            OfL[slot][h0][q] = oA[r];                                      \
            OfL[slot][h0 + 32][q] = oB[r];                                 \
        }                                                                  \
    }
#define MERGE(slot, srcw)                                                  \
    {                                                                      \
        const float mb = Mm[srcw][q], lb = Ml[srcw][q];                    \
        const float M = fmaxf(m, mb);                                      \
        const float wa = exp2f((m - M) * CEXP);                            \
        const float wb = exp2f((mb - M) * CEXP);                           \
        _Pragma("unroll")                                                  \
        for (int r = 0; r < 16; ++r) {                                     \
            const int h0 = (r & 3) + 8 * (r >> 2) + 4 * half;              \
            oA[r] = oA[r] * wa + OfL[slot][h0][q] * wb;                    \
            oB[r] = oB[r] * wa + OfL[slot][h0 + 32][q] * wb;               \
        }                                                                  \
        l = l * wa + lb * wb;                                              \
        m = M;                                                             \
    }

    if (lane < 32) { Mm[wv][q] = m; Ml[wv][q] = l; }
    if (wv >= 4) PUBLISH(wv - 4);
    __syncthreads();
    if (wv < 4) MERGE(wv, wv + 4);
    __syncthreads();
    if (wv == 2 || wv == 3) {
        PUBLISH(wv - 2);
        if (lane < 32) { Mm[wv][q] = m; Ml[wv][q] = l; }
    }
    __syncthreads();
    if (wv < 2) MERGE(wv, wv + 2);
    __syncthreads();
    if (wv == 1) {
        PUBLISH(1);
        if (lane < 32) { Mm[1][q] = m; Ml[1][q] = l; }
    }
    __syncthreads();
    if (wv == 0) {
        MERGE(1, 1);
        const float inv = 1.f / l;
#pragma unroll
        for (int r = 0; r < 16; ++r) {
            const int h0 = (r & 3) + 8 * (r >> 2) + 4 * half;
            OfL[0][h0][q] = oA[r] * inv;
            OfL[0][h0 + 32][q] = oB[r] * inv;
        }
    }
    __syncthreads();
    // coalesced final write
#pragma unroll
    for (int i = 0; i < 4; ++i) {
        const int idx = tid + 512 * i;
        const int h = idx & 63, q2 = idx >> 6;
        out[((size_t)b * TT + qbase + q2) * HH + h] = OfL[0][h][q2];
    }
#undef PUBLISH
#undef MERGE
}

extern "C" void kernel_launch(void* const* d_in, const int* in_sizes, int n_in,
                              void* d_out, int out_size, void* d_ws, size_t ws_size,
                              hipStream_t stream) {
    (void)in_sizes; (void)n_in; (void)out_size; (void)ws_size;
    const float* x  = (const float*)d_in[0];
    const float* Wq = (const float*)d_in[1];
    const float* Wk = (const float*)d_in[2];
    const float* Wv = (const float*)d_in[3];
    float* out = (float*)d_out;

    char* ws = (char*)d_ws;
    unsigned short* wTf = (unsigned short*)ws;                      // 384 KB
    unsigned short* Qf  = (unsigned short*)(ws + 393216);           // 2 MB
    unsigned short* Kf  = (unsigned short*)(ws + 393216 + 2097152); // 2 MB
    unsigned short* Vf  = (unsigned short*)(ws + 393216 + 4194304); // 2 MB

    wt_kernel<<<96, 256, 0, stream>>>(Wq, Wk, Wv, wTf);
    qkv_kernel<<<256, 512, 0, stream>>>(x, wTf, Qf, Kf, Vf);
    attn_kernel<<<512, 512, 0, stream>>>(Qf, Kf, Vf, out);
}